// Round 8
// baseline (668.142 us; speedup 1.0000x reference)
//
#include <hip/hip_runtime.h>
#include <hip/hip_bf16.h>

typedef __bf16 bf16x8 __attribute__((ext_vector_type(8)));
typedef float  f32x4  __attribute__((ext_vector_type(4)));
typedef unsigned short u16;
typedef unsigned short u16x4 __attribute__((ext_vector_type(4)));
typedef unsigned long long u64;

#define NB 1024
#define NS 1024
#define NI 32
#define NH 128
#define NCH (NS / 8)

__device__ __forceinline__ u64 pack4_bf16(f32x4 v) {
  u16x4 p;
#pragma unroll
  for (int r = 0; r < 4; ++r) p[r] = __builtin_bit_cast(u16, (__bf16)v[r]);
  return __builtin_bit_cast(u64, p);
}

__device__ __forceinline__ bf16x8 cvt8(f32x4 a, f32x4 b) {
  bf16x8 u;
#pragma unroll
  for (int j = 0; j < 4; ++j) { u[j] = (__bf16)a[j]; u[4 + j] = (__bf16)b[j]; }
  return u;
}

// Barrier that drains lgkmcnt only (no vmcnt): global loads/stores stay in flight.
__device__ __forceinline__ void lds_barrier() {
  __builtin_amdgcn_sched_barrier(0);
  asm volatile("s_waitcnt lgkmcnt(0)" ::: "memory");
  __builtin_amdgcn_s_barrier();
  asm volatile("" ::: "memory");
  __builtin_amdgcn_sched_barrier(0);
}

// Fused gate math, 3 trans ops per element (2 exp2 + 1 shared rcp):
//   z·(hh−h) = [(f−1) − h(f+1)] / [(1+e)(f+1)],  e = e^{−az}, f = e^{2·ah}
// az/ah clamped to ±15: clamp error ≤3e-7; den ≤ 2^65 (no overflow).
__device__ __forceinline__ f32x4 gru_elem(f32x4 az, f32x4 ah, f32x4 h) {
  const float NL2E  = -1.4426950408889634f;  // -log2(e)
  const float P2L2E =  2.8853900817779268f;  //  2*log2(e)
  f32x4 hn;
#pragma unroll
  for (int r = 0; r < 4; ++r) {
    float a  = fminf(15.f, fmaxf(-15.f, az[r]));
    float b  = fminf(15.f, fmaxf(-15.f, ah[r]));
    float e  = __builtin_amdgcn_exp2f(a * NL2E);
    float f  = __builtin_amdgcn_exp2f(b * P2L2E);
    float fp = f + 1.f;
    float num = __builtin_fmaf(-h[r], fp, f - 1.f);
    float den = (1.f + e) * fp;
    float rr  = __builtin_amdgcn_rcpf(den);
    hn[r] = __builtin_fmaf(num, rr, h[r]);
  }
  return hn;
}

// Block: 512 threads = 8 waves (2/SIMD). Block owns 16 batch rows for the scan.
// Wave w computes hidden cols [16w, 16w+16).
// MFMA: D'[n][m] = sum_k U[k][n] * h[m][k]  (A' = U^T slice, B' = h^T)
//   B'-frag: lane l holds h[m=l&15][k = 32kt + 8(l>>4) + j]   (one ds_read_b128)
//   D'     : lane l holds h_new[m=l&15][n = 16w + 4(l>>4) + r]
// h ping-pongs in LDS, k-major + 17-row pad (bank-uniform b128 reads).
// x fragments come straight from global per wave, batched per 8-step chunk with
// 2-7 step lead, converted progressively to bf16 register fragments (no x LDS).
__global__ __launch_bounds__(512, 1) void gru_scan(
    const float* __restrict__ x,
    const float* __restrict__ Wz, const float* __restrict__ Uz, const float* __restrict__ bz,
    const float* __restrict__ Wh, const float* __restrict__ Uh, const float* __restrict__ bh,
    float* __restrict__ out)
{
  __shared__ __align__(16) u64 hb[2][16][17][2];   // 8.5 KB

  const int tid  = threadIdx.x;
  const int lane = tid & 63;
  const int w    = tid >> 6;     // wave 0..7
  const int ml   = lane & 15;    // batch row in tile
  const int g    = lane >> 4;    // k-group / reg-group
  const int rb   = blockIdx.x * 16;

  // ---- persistent weight fragments ----
  bf16x8 ufrag[2][4];   // [gate][kt]
  bf16x8 wfrag[2];      // [gate]
  f32x4  bias2[2];      // [gate], D layout
  {
    const float* Ug[2] = {Uz, Uh};
    const float* Wg[2] = {Wz, Wh};
    const float* bg[2] = {bz, bh};
    const int n0 = 16 * w + ml;   // A'-row = hidden col
#pragma unroll
    for (int gate = 0; gate < 2; ++gate) {
#pragma unroll
      for (int kt = 0; kt < 4; ++kt)
#pragma unroll
        for (int j = 0; j < 8; ++j)
          ufrag[gate][kt][j] = (__bf16)Ug[gate][(32 * kt + 8 * g + j) * NH + n0];
#pragma unroll
      for (int j = 0; j < 8; ++j)
        wfrag[gate][j] = (__bf16)Wg[gate][(8 * g + j) * NH + n0];
      const int nb = 16 * w + 4 * g;
#pragma unroll
      for (int r = 0; r < 4; ++r) bias2[gate][r] = bg[gate][nb + r];
    }
  }

  // h0 = 0
  for (int i = tid; i < 16 * 17 * 2; i += 512) ((u64*)hb[0])[i] = 0ULL;

  const float* xrow = x + (size_t)(rb + ml) * (NS * NI) + 8 * g;  // lane's x column base

  f32x4 hv = {0.f, 0.f, 0.f, 0.f};
  float* optr = out + (size_t)(rb + ml) * NS * NH + 16 * w + 4 * g;
  const f32x4 zero4 = {0.f, 0.f, 0.f, 0.f};

  bf16x8 XA[8], XB[8];   // x fragments for current / next chunk (static idx only)
  f32x4 axz, axh;        // ax(t) = bias + x_t @ W

  {  // prologue: chunk 0 fragments + ax(0)
    f32x4 ra[16];
#pragma unroll
    for (int q = 0; q < 8; ++q) {
      const f32x4* p = (const f32x4*)(xrow + (size_t)q * NI);
      ra[2 * q] = p[0]; ra[2 * q + 1] = p[1];
    }
#pragma unroll
    for (int q = 0; q < 8; ++q) XA[q] = cvt8(ra[2 * q], ra[2 * q + 1]);
    axz = __builtin_amdgcn_mfma_f32_16x16x32_bf16(wfrag[0], XA[0], bias2[0], 0, 0, 0);
    axh = __builtin_amdgcn_mfma_f32_16x16x32_bf16(wfrag[1], XA[0], bias2[1], 0, 0, 0);
  }

  __syncthreads();   // hb[0] visible; cold full drain fine

  // One step. P = t&1 (compile-time). Consumes ax(t); produces ax(t+1) from XF.
#define GRU_STEP(P, XF)                                                                    \
  {                                                                                        \
    bf16x8 hf0 = *(const bf16x8*)&hb[P][ 0 + g][ml][0];                                    \
    bf16x8 hf1 = *(const bf16x8*)&hb[P][ 4 + g][ml][0];                                    \
    bf16x8 hf2 = *(const bf16x8*)&hb[P][ 8 + g][ml][0];                                    \
    bf16x8 hf3 = *(const bf16x8*)&hb[P][12 + g][ml][0];                                    \
    f32x4 z1 = __builtin_amdgcn_mfma_f32_16x16x32_bf16(ufrag[0][0], hf0, axz,   0, 0, 0);  \
    f32x4 h1 = __builtin_amdgcn_mfma_f32_16x16x32_bf16(ufrag[1][0], hf0, axh,   0, 0, 0);  \
    f32x4 z2 = __builtin_amdgcn_mfma_f32_16x16x32_bf16(ufrag[0][2], hf2, zero4, 0, 0, 0);  \
    f32x4 h2 = __builtin_amdgcn_mfma_f32_16x16x32_bf16(ufrag[1][2], hf2, zero4, 0, 0, 0);  \
    z1 = __builtin_amdgcn_mfma_f32_16x16x32_bf16(ufrag[0][1], hf1, z1, 0, 0, 0);           \
    h1 = __builtin_amdgcn_mfma_f32_16x16x32_bf16(ufrag[1][1], hf1, h1, 0, 0, 0);           \
    z2 = __builtin_amdgcn_mfma_f32_16x16x32_bf16(ufrag[0][3], hf3, z2, 0, 0, 0);           \
    h2 = __builtin_amdgcn_mfma_f32_16x16x32_bf16(ufrag[1][3], hf3, h2, 0, 0, 0);           \
    axz = __builtin_amdgcn_mfma_f32_16x16x32_bf16(wfrag[0], XF, bias2[0], 0, 0, 0);        \
    axh = __builtin_amdgcn_mfma_f32_16x16x32_bf16(wfrag[1], XF, bias2[1], 0, 0, 0);        \
    const f32x4 az = z1 + z2;                                                              \
    const f32x4 ah = h1 + h2;                                                              \
    f32x4 hn = gru_elem(az, ah, hv);                                                       \
    hv = hn;                                                                               \
    hb[P ^ 1][2 * w + (g >> 1)][ml][g & 1] = pack4_bf16(hn);                               \
    __builtin_nontemporal_store(hn, (f32x4*)optr);                                         \
    optr += NH;                                                                            \
  }

  // Chunk body: 8 steps consuming XC; builds XN for chunk CIDX+1.
  // Loads: A-half (steps 0-3) at tt0, B-half at tt4; cvt lead >= 2 steps everywhere.
#define CHUNK_BODY(XC, XN, CIDX)                                                           \
  {                                                                                        \
    const int c1 = ((CIDX) + 1 < NCH) ? (CIDX) + 1 : (CIDX);                               \
    const float* xp = xrow + (size_t)c1 * (8 * NI);                                        \
    f32x4 rA[8], rB[8];                                                                    \
    GRU_STEP(0, XC[1])                                                                     \
    _Pragma("unroll")                                                                      \
    for (int q = 0; q < 4; ++q) {                                                          \
      const f32x4* p = (const f32x4*)(xp + (size_t)q * NI);                                \
      rA[2 * q] = p[0]; rA[2 * q + 1] = p[1];                                              \
    }                                                                                      \
    lds_barrier();                                                                         \
    GRU_STEP(1, XC[2])                                                                     \
    lds_barrier();                                                                         \
    GRU_STEP(0, XC[3])                                                                     \
    XN[0] = cvt8(rA[0], rA[1]);                                                            \
    lds_barrier();                                                                         \
    GRU_STEP(1, XC[4])                                                                     \
    XN[1] = cvt8(rA[2], rA[3]);                                                            \
    lds_barrier();                                                                         \
    GRU_STEP(0, XC[5])                                                                     \
    _Pragma("unroll")                                                                      \
    for (int q = 0; q < 4; ++q) {                                                          \
      const f32x4* p = (const f32x4*)(xp + (size_t)(4 + q) * NI);                          \
      rB[2 * q] = p[0]; rB[2 * q + 1] = p[1];                                              \
    }                                                                                      \
    XN[2] = cvt8(rA[4], rA[5]);                                                            \
    lds_barrier();                                                                         \
    GRU_STEP(1, XC[6])                                                                     \
    XN[3] = cvt8(rA[6], rA[7]);                                                            \
    lds_barrier();                                                                         \
    GRU_STEP(0, XC[7])                                                                     \
    XN[4] = cvt8(rB[0], rB[1]);                                                            \
    XN[5] = cvt8(rB[2], rB[3]);                                                            \
    lds_barrier();                                                                         \
    GRU_STEP(1, XN[0])                                                                     \
    XN[6] = cvt8(rB[4], rB[5]);                                                            \
    XN[7] = cvt8(rB[6], rB[7]);                                                            \
    lds_barrier();                                                                         \
  }

  for (int p = 0; p < NCH / 2; ++p) {
    CHUNK_BODY(XA, XB, 2 * p)
    CHUNK_BODY(XB, XA, 2 * p + 1)
  }

  // h_last
  const size_t lbase = (size_t)NB * NS * NH + (size_t)(rb + ml) * NH + 16 * w + 4 * g;
  *(f32x4*)(out + lbase) = hv;
}

extern "C" void kernel_launch(void* const* d_in, const int* in_sizes, int n_in,
                              void* d_out, int out_size, void* d_ws, size_t ws_size,
                              hipStream_t stream) {
  const float* x  = (const float*)d_in[0];
  // d_in[1..3] = W_r, U_r, b_r: unused (r gate never affects the output)
  const float* Wz = (const float*)d_in[4];
  const float* Uz = (const float*)d_in[5];
  const float* bz = (const float*)d_in[6];
  const float* Wh = (const float*)d_in[7];
  const float* Uh = (const float*)d_in[8];
  const float* bh = (const float*)d_in[9];
  float* out = (float*)d_out;

  gru_scan<<<dim3(NB / 16), dim3(512), 0, stream>>>(x, Wz, Uz, bz, Wh, Uh, bh, out);
}